// Round 1
// baseline (571.527 us; speedup 1.0000x reference)
//
#include <hip/hip_runtime.h>
#include <hip/hip_bf16.h>

typedef __attribute__((ext_vector_type(8))) short bf16x8_t;   // 8 bf16 = 4 VGPRs (MFMA A/B frag)
typedef __attribute__((ext_vector_type(4))) float f32x4;      // MFMA C/D frag

#define S_LEN  2048
#define NB     2
#define NH     32
#define NKVH   8
#define HD     64
#define DMODEL 2048

// ---------------------------------------------------------------- fp32 -> bf16
__global__ void cvt_kernel(const float* __restrict__ in, __hip_bfloat16* __restrict__ out, int n4) {
  int i = blockIdx.x * blockDim.x + threadIdx.x;
  if (i >= n4) return;
  float4 v = ((const float4*)in)[i];
  __hip_bfloat16 o0 = __float2bfloat16(v.x), o1 = __float2bfloat16(v.y);
  __hip_bfloat16 o2 = __float2bfloat16(v.z), o3 = __float2bfloat16(v.w);
  ushort4 pk;
  pk.x = *(unsigned short*)&o0; pk.y = *(unsigned short*)&o1;
  pk.z = *(unsigned short*)&o2; pk.w = *(unsigned short*)&o3;
  ((ushort4*)out)[i] = pk;
}

// ---------------------------------------------------------------- GEMM: C = A * Bt^T
// A: M x K row-major (bf16), Bt: N x K row-major (bf16)
// EPI 0: bf16 row-major out; EPI 1: fp32 row-major out; EPI 2: bf16 Vt scatter (B,KVH,HD,S)
template<int EPI>
__global__ __launch_bounds__(256)
void gemm_bt(const __hip_bfloat16* __restrict__ A,
             const __hip_bfloat16* __restrict__ Bt,
             void* __restrict__ Cv, int M, int N, int K)
{
  __shared__ __align__(16) __hip_bfloat16 As[128][32];
  __shared__ __align__(16) __hip_bfloat16 Bs[128][32];

  const int tid  = threadIdx.x;
  const int lane = tid & 63;
  const int w    = tid >> 6;          // wave 0..3
  const int wr   = (w >> 1) * 64;     // wave row offset in tile
  const int wc   = (w & 1) * 64;      // wave col offset in tile
  const int brow = blockIdx.y * 128;
  const int bcol = blockIdx.x * 128;
  const int fr   = lane & 15;         // fragment row/col index
  const int fg   = lane >> 4;         // k-group (8 contiguous k each)

  const f32x4 fz = {0.f, 0.f, 0.f, 0.f};
  f32x4 acc[4][4];
#pragma unroll
  for (int i = 0; i < 4; ++i)
#pragma unroll
    for (int j = 0; j < 4; ++j) acc[i][j] = fz;

  // staging: thread t covers rows {t/4, t/4+64}, 8 bf16 at col (t&3)*8
  const int sr = tid >> 2;
  const int sc = (tid & 3) * 8;
  const __hip_bfloat16* Ag = A  + (size_t)(brow + sr) * K + sc;
  const __hip_bfloat16* Bg = Bt + (size_t)(bcol + sr) * K + sc;

  for (int kt = 0; kt < K; kt += 32) {
    __syncthreads();
    bf16x8_t a0 = *(const bf16x8_t*)(Ag + kt);
    bf16x8_t a1 = *(const bf16x8_t*)(Ag + (size_t)64 * K + kt);
    bf16x8_t b0 = *(const bf16x8_t*)(Bg + kt);
    bf16x8_t b1 = *(const bf16x8_t*)(Bg + (size_t)64 * K + kt);
    *(bf16x8_t*)&As[sr][sc]      = a0;
    *(bf16x8_t*)&As[sr + 64][sc] = a1;
    *(bf16x8_t*)&Bs[sr][sc]      = b0;
    *(bf16x8_t*)&Bs[sr + 64][sc] = b1;
    __syncthreads();

    bf16x8_t af[4], bfr[4];
#pragma unroll
    for (int mi = 0; mi < 4; ++mi)
      af[mi] = *(const bf16x8_t*)&As[wr + mi * 16 + fr][fg * 8];
#pragma unroll
    for (int ni = 0; ni < 4; ++ni)
      bfr[ni] = *(const bf16x8_t*)&Bs[wc + ni * 16 + fr][fg * 8];
#pragma unroll
    for (int mi = 0; mi < 4; ++mi)
#pragma unroll
      for (int ni = 0; ni < 4; ++ni)
        acc[mi][ni] = __builtin_amdgcn_mfma_f32_16x16x32_bf16(af[mi], bfr[ni], acc[mi][ni], 0, 0, 0);
  }

  // epilogue: lane reg r -> row (fg*4+r), col fr  [verified C/D layout]
#pragma unroll
  for (int mi = 0; mi < 4; ++mi) {
#pragma unroll
    for (int ni = 0; ni < 4; ++ni) {
      const int row0 = brow + wr + mi * 16 + fg * 4;
      const int col  = bcol + wc + ni * 16 + fr;
      if (EPI == 0) {
        __hip_bfloat16* C = (__hip_bfloat16*)Cv;
#pragma unroll
        for (int r = 0; r < 4; ++r)
          C[(size_t)(row0 + r) * N + col] = __float2bfloat16(acc[mi][ni][r]);
      } else if (EPI == 1) {
        float* C = (float*)Cv;
#pragma unroll
        for (int r = 0; r < 4; ++r)
          C[(size_t)(row0 + r) * N + col] = acc[mi][ni][r];
      } else {
        // V GEMM: row = b*S+s, col = kvh*64+d  ->  Vt[b][kvh][d][s], 4 consecutive s = 8B store
        __hip_bfloat16* C = (__hip_bfloat16*)Cv;
        const int b = row0 >> 11, s = row0 & 2047;
        const int kvh = col >> 6, d = col & 63;
        __hip_bfloat16 v0 = __float2bfloat16(acc[mi][ni][0]);
        __hip_bfloat16 v1 = __float2bfloat16(acc[mi][ni][1]);
        __hip_bfloat16 v2 = __float2bfloat16(acc[mi][ni][2]);
        __hip_bfloat16 v3 = __float2bfloat16(acc[mi][ni][3]);
        ushort4 pk;
        pk.x = *(unsigned short*)&v0; pk.y = *(unsigned short*)&v1;
        pk.z = *(unsigned short*)&v2; pk.w = *(unsigned short*)&v3;
        *(ushort4*)&C[(((size_t)b * NKVH + kvh) * HD + d) * S_LEN + s] = pk;
      }
    }
  }
}

// ---------------------------------------------------------------- RoPE in-place on Q and K
__global__ void rope_kernel(__hip_bfloat16* __restrict__ Qb, __hip_bfloat16* __restrict__ Kb,
                            const float* __restrict__ cosb, const float* __restrict__ sinb)
{
  const int NQ = NB * S_LEN * NH * 32;     // q pairs
  const int NK = NB * S_LEN * NKVH * 32;   // k pairs
  int idx = blockIdx.x * blockDim.x + threadIdx.x;
  if (idx >= NQ + NK) return;
  __hip_bfloat16* base; int row, d;
  if (idx < NQ) {
    row = idx >> 10;                       // / (NH*32)
    int rem = idx & 1023;
    base = Qb + (size_t)row * (NH * HD) + (rem >> 5) * HD;
    d = rem & 31;
  } else {
    int j = idx - NQ;
    row = j >> 8;                          // / (NKVH*32)
    int rem = j & 255;
    base = Kb + (size_t)row * (NKVH * HD) + (rem >> 5) * HD;
    d = rem & 31;
  }
  float c = cosb[(size_t)row * HD + d];
  float s = sinb[(size_t)row * HD + d];   // sin[d+32] == sin[d], cos likewise
  float x0 = __bfloat162float(base[d]);
  float x1 = __bfloat162float(base[d + 32]);
  base[d]      = __float2bfloat16(x0 * c - x1 * s);
  base[d + 32] = __float2bfloat16(x1 * c + x0 * s);
}

// ---------------------------------------------------------------- flash attention (causal, GQA)
// Q: (B*S, NH*HD) roped bf16; K: (B*S, NKVH*HD) roped bf16; Vt: (B,NKVH,HD,S) bf16
// O: (B*S, NH*HD) bf16.  Block: 4 waves x 16 q-rows = 64 q; key tiles of 64.
__global__ __launch_bounds__(256)
void attn_kernel(const __hip_bfloat16* __restrict__ Q, const __hip_bfloat16* __restrict__ K,
                 const __hip_bfloat16* __restrict__ Vt, __hip_bfloat16* __restrict__ O)
{
  __shared__ __align__(16) __hip_bfloat16 Ks[64][72];       // [key][feat], pad -> conflict-free
  __shared__ __align__(16) __hip_bfloat16 Vs[64][72];       // [feat][key]
  __shared__ __align__(16) __hip_bfloat16 Ps[4][16][72];    // per-wave P tile

  const int lane = threadIdx.x & 63;
  const int w    = threadIdx.x >> 6;
  const int fr   = lane & 15;
  const int fg   = lane >> 4;
  const int bh   = blockIdx.y;
  const int b    = bh >> 5;
  const int h    = bh & 31;
  const int kvh  = h >> 2;                 // groups = NH/NKVH = 4
  const int qt     = blockIdx.x;
  const int qbase  = qt * 64;

  const __hip_bfloat16* Qg = Q + ((size_t)(b * S_LEN + qbase)) * DMODEL + h * HD;
  const __hip_bfloat16* Kg = K + (size_t)b * S_LEN * (NKVH * HD) + kvh * HD;
  const __hip_bfloat16* Vg = Vt + ((size_t)(b * NKVH + kvh)) * HD * S_LEN;

  // Q fragments (16 rows x 64 k), kept in registers
  bf16x8_t qf[2];
#pragma unroll
  for (int kk = 0; kk < 2; ++kk)
    qf[kk] = *(const bf16x8_t*)(Qg + (size_t)(w * 16 + fr) * DMODEL + kk * 32 + fg * 8);

  const f32x4 fz = {0.f, 0.f, 0.f, 0.f};
  f32x4 acc[4]; float m_[4], l_[4];
#pragma unroll
  for (int i = 0; i < 4; ++i) { acc[i] = fz; m_[i] = -1e30f; l_[i] = 0.f; }

  const int ktiles = qt + 1;
  for (int t = 0; t < ktiles; ++t) {
    const int kt = t * 64;
    __syncthreads();
    {   // stage K tile [64 keys][64 feat] and Vt tile [64 feat][64 keys]
      const int r = threadIdx.x >> 2, c = (threadIdx.x & 3) * 16;
      const bf16x8_t* ksrc = (const bf16x8_t*)(Kg + (size_t)(kt + r) * (NKVH * HD) + c);
      *(bf16x8_t*)&Ks[r][c]     = ksrc[0];
      *(bf16x8_t*)&Ks[r][c + 8] = ksrc[1];
      const bf16x8_t* vsrc = (const bf16x8_t*)(Vg + (size_t)r * S_LEN + kt + c);
      *(bf16x8_t*)&Vs[r][c]     = vsrc[0];
      *(bf16x8_t*)&Vs[r][c + 8] = vsrc[1];
    }
    __syncthreads();

    // QK^T: s[c] = 16 q-rows x 16 keys
    f32x4 sc[4];
#pragma unroll
    for (int c = 0; c < 4; ++c) {
      bf16x8_t k0 = *(const bf16x8_t*)&Ks[c * 16 + fr][fg * 8];
      bf16x8_t k1 = *(const bf16x8_t*)&Ks[c * 16 + fr][32 + fg * 8];
      sc[c] = __builtin_amdgcn_mfma_f32_16x16x32_bf16(qf[0], k0, fz, 0, 0, 0);
      sc[c] = __builtin_amdgcn_mfma_f32_16x16x32_bf16(qf[1], k1, sc[c], 0, 0, 0);
    }

    // scale + causal mask + row stats (row = qbase + w*16 + fg*4 + r; col = kt + c*16 + fr)
    float p[4][4], tm[4];
#pragma unroll
    for (int r = 0; r < 4; ++r) tm[r] = -1e30f;
#pragma unroll
    for (int c = 0; c < 4; ++c)
#pragma unroll
      for (int r = 0; r < 4; ++r) {
        float v = sc[c][r] * 0.125f;
        const int kcol = kt + c * 16 + fr;
        const int qrow = qbase + w * 16 + fg * 4 + r;
        if (kcol > qrow) v = -1e30f;
        p[c][r] = v;
        tm[r] = fmaxf(tm[r], v);
      }
#pragma unroll
    for (int r = 0; r < 4; ++r)
#pragma unroll
      for (int d = 1; d < 16; d <<= 1)
        tm[r] = fmaxf(tm[r], __shfl_xor(tm[r], d));

    float sf[4];
#pragma unroll
    for (int r = 0; r < 4; ++r) {
      float mnew = fmaxf(m_[r], tm[r]);
      sf[r] = __expf(m_[r] - mnew);
      m_[r] = mnew;
    }
    float ts[4] = {0.f, 0.f, 0.f, 0.f};
#pragma unroll
    for (int c = 0; c < 4; ++c)
#pragma unroll
      for (int r = 0; r < 4; ++r) {
        p[c][r] = __expf(p[c][r] - m_[r]);
        ts[r] += p[c][r];
      }
#pragma unroll
    for (int r = 0; r < 4; ++r) {
#pragma unroll
      for (int d = 1; d < 16; d <<= 1) ts[r] += __shfl_xor(ts[r], d);
      l_[r] = l_[r] * sf[r] + ts[r];
    }
#pragma unroll
    for (int fc = 0; fc < 4; ++fc)
#pragma unroll
      for (int r = 0; r < 4; ++r) acc[fc][r] *= sf[r];

    // P -> LDS (per-wave), then PV via MFMA
#pragma unroll
    for (int c = 0; c < 4; ++c)
#pragma unroll
      for (int r = 0; r < 4; ++r)
        Ps[w][fg * 4 + r][c * 16 + fr] = __float2bfloat16(p[c][r]);
    __syncthreads();   // conservative: guarantees P writes visible before frag reads

#pragma unroll
    for (int kk = 0; kk < 2; ++kk) {
      bf16x8_t pa = *(const bf16x8_t*)&Ps[w][fr][kk * 32 + fg * 8];
#pragma unroll
      for (int fc = 0; fc < 4; ++fc) {
        bf16x8_t vf = *(const bf16x8_t*)&Vs[fc * 16 + fr][kk * 32 + fg * 8];
        acc[fc] = __builtin_amdgcn_mfma_f32_16x16x32_bf16(pa, vf, acc[fc], 0, 0, 0);
      }
    }
  }

  // epilogue: O[(b*S + q), h*64 + feat] = acc / l
#pragma unroll
  for (int fc = 0; fc < 4; ++fc)
#pragma unroll
    for (int r = 0; r < 4; ++r) {
      const size_t row = (size_t)(b * S_LEN + qbase + w * 16 + fg * 4 + r);
      O[row * DMODEL + h * HD + fc * 16 + fr] = __float2bfloat16(acc[fc][r] / l_[r]);
    }
}

// ---------------------------------------------------------------- launch
extern "C" void kernel_launch(void* const* d_in, const int* in_sizes, int n_in,
                              void* d_out, int out_size, void* d_ws, size_t ws_size,
                              hipStream_t stream)
{
  const float* x    = (const float*)d_in[0];
  const float* cosb = (const float*)d_in[1];
  const float* sinb = (const float*)d_in[2];
  const float* Wq   = (const float*)d_in[3];
  const float* Wk   = (const float*)d_in[4];
  const float* Wv   = (const float*)d_in[5];
  const float* Wo   = (const float*)d_in[6];
  float* out = (float*)d_out;

  char* p = (char*)d_ws;
  __hip_bfloat16* x_bf    = (__hip_bfloat16*)p; p += (size_t)NB * S_LEN * DMODEL * 2;
  __hip_bfloat16* Wq_bf   = (__hip_bfloat16*)p; p += (size_t)NH * HD * DMODEL * 2;
  __hip_bfloat16* Wk_bf   = (__hip_bfloat16*)p; p += (size_t)NKVH * HD * DMODEL * 2;
  __hip_bfloat16* Wv_bf   = (__hip_bfloat16*)p; p += (size_t)NKVH * HD * DMODEL * 2;
  __hip_bfloat16* Wo_bf   = (__hip_bfloat16*)p; p += (size_t)DMODEL * NH * HD * 2;
  __hip_bfloat16* Q_bf    = (__hip_bfloat16*)p; p += (size_t)NB * S_LEN * NH * HD * 2;
  __hip_bfloat16* K_bf    = (__hip_bfloat16*)p; p += (size_t)NB * S_LEN * NKVH * HD * 2;
  __hip_bfloat16* Vt_bf   = (__hip_bfloat16*)p; p += (size_t)NB * NKVH * HD * S_LEN * 2;
  __hip_bfloat16* attn_bf = (__hip_bfloat16*)p; p += (size_t)NB * S_LEN * NH * HD * 2;

  auto cvt = [&](const float* src, __hip_bfloat16* dst, size_t n) {
    int n4 = (int)(n / 4);
    cvt_kernel<<<(n4 + 255) / 256, 256, 0, stream>>>(src, dst, n4);
  };
  cvt(x,  x_bf,  (size_t)NB * S_LEN * DMODEL);
  cvt(Wq, Wq_bf, (size_t)NH * HD * DMODEL);
  cvt(Wk, Wk_bf, (size_t)NKVH * HD * DMODEL);
  cvt(Wv, Wv_bf, (size_t)NKVH * HD * DMODEL);
  cvt(Wo, Wo_bf, (size_t)DMODEL * NH * HD);

  const dim3 blk(256);
  // Q/K/V projections (x: 4096x2048; W: (O,D) row-major = Bt layout)
  gemm_bt<0><<<dim3(DMODEL / 128, (NB * S_LEN) / 128), blk, 0, stream>>>(x_bf, Wq_bf, Q_bf, NB * S_LEN, DMODEL, DMODEL);
  gemm_bt<0><<<dim3((NKVH * HD) / 128, (NB * S_LEN) / 128), blk, 0, stream>>>(x_bf, Wk_bf, K_bf, NB * S_LEN, NKVH * HD, DMODEL);
  gemm_bt<2><<<dim3((NKVH * HD) / 128, (NB * S_LEN) / 128), blk, 0, stream>>>(x_bf, Wv_bf, Vt_bf, NB * S_LEN, NKVH * HD, DMODEL);

  {
    int total = NB * S_LEN * (NH + NKVH) * 32;
    rope_kernel<<<(total + 255) / 256, 256, 0, stream>>>(Q_bf, K_bf, cosb, sinb);
  }

  attn_kernel<<<dim3(S_LEN / 64, NB * NH), blk, 0, stream>>>(Q_bf, K_bf, Vt_bf, attn_bf);

  // output projection -> fp32 d_out
  gemm_bt<1><<<dim3(DMODEL / 128, (NB * S_LEN) / 128), blk, 0, stream>>>(attn_bf, Wo_bf, out, NB * S_LEN, DMODEL, DMODEL);
}

// Round 2
// 411.462 us; speedup vs baseline: 1.3890x; 1.3890x over previous
//
#include <hip/hip_runtime.h>
#include <hip/hip_bf16.h>

typedef __attribute__((ext_vector_type(8))) short bf16x8_t;   // 8 bf16 = 4 VGPRs (MFMA A/B frag)
typedef __attribute__((ext_vector_type(4))) float f32x4;      // MFMA C/D frag

#define S_LEN  2048
#define NB     2
#define NH     32
#define NKVH   8
#define HD     64
#define DMODEL 2048

// async global->LDS, 16B per lane; lds dst is wave-uniform base + lane*16
__device__ __forceinline__ void gload16(const __hip_bfloat16* g, __hip_bfloat16* l) {
  __builtin_amdgcn_global_load_lds(
      (const __attribute__((address_space(1))) void*)g,
      (__attribute__((address_space(3))) void*)l, 16, 0, 0);
}

// ---------------------------------------------------------------- fp32 -> bf16
__global__ void cvt_kernel(const float* __restrict__ in, __hip_bfloat16* __restrict__ out, int n4) {
  int i = blockIdx.x * blockDim.x + threadIdx.x;
  if (i >= n4) return;
  float4 v = ((const float4*)in)[i];
  __hip_bfloat16 o0 = __float2bfloat16(v.x), o1 = __float2bfloat16(v.y);
  __hip_bfloat16 o2 = __float2bfloat16(v.z), o3 = __float2bfloat16(v.w);
  ushort4 pk;
  pk.x = *(unsigned short*)&o0; pk.y = *(unsigned short*)&o1;
  pk.z = *(unsigned short*)&o2; pk.w = *(unsigned short*)&o3;
  ((ushort4*)out)[i] = pk;
}

// ---------------------------------------------------------------- fused QKV projection + RoPE
// A = x_bf (M=4096 x K=2048). Virtual Bt = [Wq (2048 rows) | Wk (512) | Wv (512)], all (O,D) row-major.
// Q path: rope -> Q_bf (M,2048). K path: rope -> K_bf (M,512). V path: -> Vt_bf (B,KVH,HD,S).
__global__ __launch_bounds__(256)
void gemm_qkv(const __hip_bfloat16* __restrict__ A,
              const __hip_bfloat16* __restrict__ Wq,
              const __hip_bfloat16* __restrict__ Wk,
              const __hip_bfloat16* __restrict__ Wv,
              __hip_bfloat16* __restrict__ Qo,
              __hip_bfloat16* __restrict__ Ko,
              __hip_bfloat16* __restrict__ Vto,
              const float* __restrict__ cosb,
              const float* __restrict__ sinb)
{
  __shared__ __align__(16) __hip_bfloat16 As[128][32];
  __shared__ __align__(16) __hip_bfloat16 Bs[128][32];
  const int K = DMODEL;

  const int tid  = threadIdx.x;
  const int lane = tid & 63;
  const int w    = tid >> 6;
  const int wr   = (w >> 1) * 64;
  const int wc   = (w & 1) * 64;
  const int brow = blockIdx.y * 128;
  const int fr   = lane & 15;
  const int fg   = lane >> 4;

  // block-uniform selection of weight slice
  const int bc = blockIdx.x * 128;
  const __hip_bfloat16* Bt; int bcol; int path;
  if (bc < 2048)      { Bt = Wq; bcol = bc;        path = 0; }
  else if (bc < 2560) { Bt = Wk; bcol = bc - 2048; path = 1; }
  else                { Bt = Wv; bcol = bc - 2560; path = 2; }

  const f32x4 fz = {0.f, 0.f, 0.f, 0.f};
  f32x4 acc[4][4];
#pragma unroll
  for (int i = 0; i < 4; ++i)
#pragma unroll
    for (int j = 0; j < 4; ++j) acc[i][j] = fz;

  // global_load_lds staging: wave w stages rows [w*32, w*32+32) of A and Bt (2 instrs each)
  const int lrow = lane >> 2;           // 0..15
  const int lcol = (lane & 3) * 8;      // bf16 elements (16B)
  const __hip_bfloat16* Ag = A  + (size_t)(brow + w * 32 + lrow) * K + lcol;
  const __hip_bfloat16* Bg = Bt + (size_t)(bcol + w * 32 + lrow) * K + lcol;
  __hip_bfloat16* lA0 = &As[w * 32][0];
  __hip_bfloat16* lA1 = &As[w * 32 + 16][0];
  __hip_bfloat16* lB0 = &Bs[w * 32][0];
  __hip_bfloat16* lB1 = &Bs[w * 32 + 16][0];

  for (int kt = 0; kt < K; kt += 32) {
    __syncthreads();
    gload16(Ag + kt, lA0);
    gload16(Ag + (size_t)16 * K + kt, lA1);
    gload16(Bg + kt, lB0);
    gload16(Bg + (size_t)16 * K + kt, lB1);
    asm volatile("s_waitcnt vmcnt(0)" ::: "memory");
    __syncthreads();

    bf16x8_t af[4], bfr[4];
#pragma unroll
    for (int mi = 0; mi < 4; ++mi)
      af[mi] = *(const bf16x8_t*)&As[wr + mi * 16 + fr][fg * 8];
#pragma unroll
    for (int ni = 0; ni < 4; ++ni)
      bfr[ni] = *(const bf16x8_t*)&Bs[wc + ni * 16 + fr][fg * 8];
#pragma unroll
    for (int mi = 0; mi < 4; ++mi)
#pragma unroll
      for (int ni = 0; ni < 4; ++ni)
        acc[mi][ni] = __builtin_amdgcn_mfma_f32_16x16x32_bf16(af[mi], bfr[ni], acc[mi][ni], 0, 0, 0);
  }

  // epilogue: lane reg r -> row (fg*4+r), col fr
  if (path == 2) {
    // V: row = b*S+s, col = kvh*64+d -> Vt[b][kvh][d][s], 4 consecutive s per lane
#pragma unroll
    for (int mi = 0; mi < 4; ++mi) {
#pragma unroll
      for (int ni = 0; ni < 4; ++ni) {
        const int row0 = brow + wr + mi * 16 + fg * 4;
        const int col  = bcol + wc + ni * 16 + fr;
        const int b = row0 >> 11, s = row0 & 2047;
        const int kvh = col >> 6, d = col & 63;
        __hip_bfloat16 v0 = __float2bfloat16(acc[mi][ni][0]);
        __hip_bfloat16 v1 = __float2bfloat16(acc[mi][ni][1]);
        __hip_bfloat16 v2 = __float2bfloat16(acc[mi][ni][2]);
        __hip_bfloat16 v3 = __float2bfloat16(acc[mi][ni][3]);
        ushort4 pk;
        pk.x = *(unsigned short*)&v0; pk.y = *(unsigned short*)&v1;
        pk.z = *(unsigned short*)&v2; pk.w = *(unsigned short*)&v3;
        *(ushort4*)&Vto[(((size_t)b * NKVH + kvh) * HD + d) * S_LEN + s] = pk;
      }
    }
  } else {
    __hip_bfloat16* C = (path == 0) ? Qo : Ko;
    const int N = (path == 0) ? (NH * HD) : (NKVH * HD);
#pragma unroll
    for (int mi = 0; mi < 4; ++mi) {
#pragma unroll
      for (int r = 0; r < 4; ++r) {
        const int row = brow + wr + mi * 16 + fg * 4 + r;
#pragma unroll
        for (int ni = 0; ni < 2; ++ni) {   // ni pairs with ni+2 : (d, d+32) same head, same lane
          const int colL = bcol + wc + ni * 16 + fr;
          const int d    = (colL & 63);    // < 32
          const float c  = cosb[(size_t)row * HD + d];
          const float sn = sinb[(size_t)row * HD + d];
          const float v0 = acc[mi][ni][r];
          const float v1 = acc[mi][ni + 2][r];
          C[(size_t)row * N + colL]      = __float2bfloat16(v0 * c - v1 * sn);
          C[(size_t)row * N + colL + 32] = __float2bfloat16(v1 * c + v0 * sn);
        }
      }
    }
  }
}

// ---------------------------------------------------------------- output projection (fp32 out)
__global__ __launch_bounds__(256)
void gemm_o(const __hip_bfloat16* __restrict__ A,
            const __hip_bfloat16* __restrict__ Bt,
            float* __restrict__ C)
{
  __shared__ __align__(16) __hip_bfloat16 As[128][32];
  __shared__ __align__(16) __hip_bfloat16 Bs[128][32];
  const int K = DMODEL, N = DMODEL;

  const int tid  = threadIdx.x;
  const int lane = tid & 63;
  const int w    = tid >> 6;
  const int wr   = (w >> 1) * 64;
  const int wc   = (w & 1) * 64;
  const int brow = blockIdx.y * 128;
  const int bcol = blockIdx.x * 128;
  const int fr   = lane & 15;
  const int fg   = lane >> 4;

  const f32x4 fz = {0.f, 0.f, 0.f, 0.f};
  f32x4 acc[4][4];
#pragma unroll
  for (int i = 0; i < 4; ++i)
#pragma unroll
    for (int j = 0; j < 4; ++j) acc[i][j] = fz;

  const int lrow = lane >> 2;
  const int lcol = (lane & 3) * 8;
  const __hip_bfloat16* Ag = A  + (size_t)(brow + w * 32 + lrow) * K + lcol;
  const __hip_bfloat16* Bg = Bt + (size_t)(bcol + w * 32 + lrow) * K + lcol;
  __hip_bfloat16* lA0 = &As[w * 32][0];
  __hip_bfloat16* lA1 = &As[w * 32 + 16][0];
  __hip_bfloat16* lB0 = &Bs[w * 32][0];
  __hip_bfloat16* lB1 = &Bs[w * 32 + 16][0];

  for (int kt = 0; kt < K; kt += 32) {
    __syncthreads();
    gload16(Ag + kt, lA0);
    gload16(Ag + (size_t)16 * K + kt, lA1);
    gload16(Bg + kt, lB0);
    gload16(Bg + (size_t)16 * K + kt, lB1);
    asm volatile("s_waitcnt vmcnt(0)" ::: "memory");
    __syncthreads();

    bf16x8_t af[4], bfr[4];
#pragma unroll
    for (int mi = 0; mi < 4; ++mi)
      af[mi] = *(const bf16x8_t*)&As[wr + mi * 16 + fr][fg * 8];
#pragma unroll
    for (int ni = 0; ni < 4; ++ni)
      bfr[ni] = *(const bf16x8_t*)&Bs[wc + ni * 16 + fr][fg * 8];
#pragma unroll
    for (int mi = 0; mi < 4; ++mi)
#pragma unroll
      for (int ni = 0; ni < 4; ++ni)
        acc[mi][ni] = __builtin_amdgcn_mfma_f32_16x16x32_bf16(af[mi], bfr[ni], acc[mi][ni], 0, 0, 0);
  }

#pragma unroll
  for (int mi = 0; mi < 4; ++mi)
#pragma unroll
    for (int ni = 0; ni < 4; ++ni) {
      const int row0 = brow + wr + mi * 16 + fg * 4;
      const int col  = bcol + wc + ni * 16 + fr;
#pragma unroll
      for (int r = 0; r < 4; ++r)
        C[(size_t)(row0 + r) * N + col] = acc[mi][ni][r];
    }
}

// ---------------------------------------------------------------- flash attention (causal, GQA)
// Swapped-QK layout: sc = mfma(K_frag, Q_frag) -> lane owns q = lane&15, 16 key-scores.
// Q: (B*S, 2048) roped bf16; K: (B*S, 512) roped bf16; Vt: (B,KVH,HD,S) bf16; O: (B*S, 2048) bf16.
__global__ __launch_bounds__(256)
void attn_kernel(const __hip_bfloat16* __restrict__ Q, const __hip_bfloat16* __restrict__ K,
                 const __hip_bfloat16* __restrict__ Vt, __hip_bfloat16* __restrict__ O)
{
  __shared__ __align__(16) __hip_bfloat16 Ks[64][72];       // [key][feat]
  __shared__ __align__(16) __hip_bfloat16 Vs[64][72];       // [feat][key]
  __shared__ __align__(16) __hip_bfloat16 Ps[4][16][72];    // per-wave [q][key]

  const int lane = threadIdx.x & 63;
  const int w    = threadIdx.x >> 6;
  const int fr   = lane & 15;
  const int fg   = lane >> 4;
  const int bh   = blockIdx.y;
  const int b    = bh >> 5;
  const int h    = bh & 31;
  const int kvh  = h >> 2;
  const int qt    = gridDim.x - 1 - blockIdx.x;   // LPT: heavy blocks dispatch first
  const int qbase = qt * 64;

  const __hip_bfloat16* Qg = Q + ((size_t)(b * S_LEN + qbase)) * DMODEL + h * HD;
  const __hip_bfloat16* Kg = K + (size_t)b * S_LEN * (NKVH * HD) + kvh * HD;
  const __hip_bfloat16* Vg = Vt + ((size_t)(b * NKVH + kvh)) * HD * S_LEN;

  // Q fragments: B-operand, col q = fr, k = fg*8+e  (16 q-rows x 64 feat per wave)
  bf16x8_t qf[2];
#pragma unroll
  for (int kk = 0; kk < 2; ++kk)
    qf[kk] = *(const bf16x8_t*)(Qg + (size_t)(w * 16 + fr) * DMODEL + kk * 32 + fg * 8);

  const f32x4 fz = {0.f, 0.f, 0.f, 0.f};
  f32x4 acc[4];
#pragma unroll
  for (int i = 0; i < 4; ++i) acc[i] = fz;
  float m_ = -1e30f, l_ = 0.f;        // stats for q = fr (per lane)

  const int qrow = qbase + w * 16 + fr;

  const int ktiles = qt + 1;
  for (int t = 0; t < ktiles; ++t) {
    const int kt = t * 64;
    __syncthreads();
    {   // stage K tile [64 keys][64 feat] and Vt tile [64 feat][64 keys]
      const int r = threadIdx.x >> 2, c = (threadIdx.x & 3) * 16;
      const bf16x8_t* ksrc = (const bf16x8_t*)(Kg + (size_t)(kt + r) * (NKVH * HD) + c);
      *(bf16x8_t*)&Ks[r][c]     = ksrc[0];
      *(bf16x8_t*)&Ks[r][c + 8] = ksrc[1];
      const bf16x8_t* vsrc = (const bf16x8_t*)(Vg + (size_t)r * S_LEN + kt + c);
      *(bf16x8_t*)&Vs[r][c]     = vsrc[0];
      *(bf16x8_t*)&Vs[r][c + 8] = vsrc[1];
    }
    __syncthreads();

    // QK^T swapped: sc[c] rows = keys c*16 + fg*4 + r, col = q = fr
    f32x4 sc[4];
#pragma unroll
    for (int c = 0; c < 4; ++c) {
      bf16x8_t k0 = *(const bf16x8_t*)&Ks[c * 16 + fr][fg * 8];
      bf16x8_t k1 = *(const bf16x8_t*)&Ks[c * 16 + fr][32 + fg * 8];
      sc[c] = __builtin_amdgcn_mfma_f32_16x16x32_bf16(k0, qf[0], fz, 0, 0, 0);
      sc[c] = __builtin_amdgcn_mfma_f32_16x16x32_bf16(k1, qf[1], sc[c], 0, 0, 0);
    }

    // in-lane softmax over the 16 held keys; q = fr
    float p[4][4];
    float tm = -1e30f;
#pragma unroll
    for (int c = 0; c < 4; ++c)
#pragma unroll
      for (int r = 0; r < 4; ++r) {
        float v = sc[c][r] * 0.125f;
        const int kcol = kt + c * 16 + fg * 4 + r;
        if (kcol > qrow) v = -1e30f;
        p[c][r] = v;
        tm = fmaxf(tm, v);
      }
    tm = fmaxf(tm, __shfl_xor(tm, 16));
    tm = fmaxf(tm, __shfl_xor(tm, 32));

    const float mnew = fmaxf(m_, tm);
    const float sf = __expf(m_ - mnew);
    m_ = mnew;

    float ts = 0.f;
#pragma unroll
    for (int c = 0; c < 4; ++c)
#pragma unroll
      for (int r = 0; r < 4; ++r) {
        p[c][r] = __expf(p[c][r] - m_);
        ts += p[c][r];
      }
    ts += __shfl_xor(ts, 16);
    ts += __shfl_xor(ts, 32);
    l_ = l_ * sf + ts;

    // redistribute sf to acc rows (acc row q_local = fg*4 + r; stats live at lane fr == q_local)
    float sfv[4];
#pragma unroll
    for (int r = 0; r < 4; ++r) sfv[r] = __shfl(sf, fg * 4 + r);
#pragma unroll
    for (int fc = 0; fc < 4; ++fc)
#pragma unroll
      for (int r = 0; r < 4; ++r) acc[fc][r] *= sfv[r];

    // P -> per-wave LDS [q][key], packed 4 keys per 8B store (no block barrier needed)
#pragma unroll
    for (int c = 0; c < 4; ++c) {
      __hip_bfloat16 b0 = __float2bfloat16(p[c][0]);
      __hip_bfloat16 b1 = __float2bfloat16(p[c][1]);
      __hip_bfloat16 b2 = __float2bfloat16(p[c][2]);
      __hip_bfloat16 b3 = __float2bfloat16(p[c][3]);
      ushort4 pk;
      pk.x = *(unsigned short*)&b0; pk.y = *(unsigned short*)&b1;
      pk.z = *(unsigned short*)&b2; pk.w = *(unsigned short*)&b3;
      *(ushort4*)&Ps[w][fr][c * 16 + fg * 4] = pk;
    }

    // PV: A = P (row q = fr, k = key), B = V (col d = fr, k = key)
#pragma unroll
    for (int kk = 0; kk < 2; ++kk) {
      bf16x8_t pa = *(const bf16x8_t*)&Ps[w][fr][kk * 32 + fg * 8];
#pragma unroll
      for (int fc = 0; fc < 4; ++fc) {
        bf16x8_t vf = *(const bf16x8_t*)&Vs[fc * 16 + fr][kk * 32 + fg * 8];
        acc[fc] = __builtin_amdgcn_mfma_f32_16x16x32_bf16(pa, vf, acc[fc], 0, 0, 0);
      }
    }
  }

  // epilogue: acc row q_local = fg*4+r, col d = fc*16+fr; l lives at lane q_local
  float lv[4];
#pragma unroll
  for (int r = 0; r < 4; ++r) lv[r] = __builtin_amdgcn_rcpf(__shfl(l_, fg * 4 + r));
#pragma unroll
  for (int fc = 0; fc < 4; ++fc)
#pragma unroll
    for (int r = 0; r < 4; ++r) {
      const size_t row = (size_t)(b * S_LEN + qbase + w * 16 + fg * 4 + r);
      O[row * DMODEL + h * HD + fc * 16 + fr] = __float2bfloat16(acc[fc][r] * lv[r]);
    }
}

// ---------------------------------------------------------------- launch
extern "C" void kernel_launch(void* const* d_in, const int* in_sizes, int n_in,
                              void* d_out, int out_size, void* d_ws, size_t ws_size,
                              hipStream_t stream)
{
  const float* x    = (const float*)d_in[0];
  const float* cosb = (const float*)d_in[1];
  const float* sinb = (const float*)d_in[2];
  const float* Wq   = (const float*)d_in[3];
  const float* Wk   = (const float*)d_in[4];
  const float* Wv   = (const float*)d_in[5];
  const float* Wo   = (const float*)d_in[6];
  float* out = (float*)d_out;

  char* p = (char*)d_ws;
  __hip_bfloat16* x_bf    = (__hip_bfloat16*)p; p += (size_t)NB * S_LEN * DMODEL * 2;
  __hip_bfloat16* Wq_bf   = (__hip_bfloat16*)p; p += (size_t)NH * HD * DMODEL * 2;
  __hip_bfloat16* Wk_bf   = (__hip_bfloat16*)p; p += (size_t)NKVH * HD * DMODEL * 2;
  __hip_bfloat16* Wv_bf   = (__hip_bfloat16*)p; p += (size_t)NKVH * HD * DMODEL * 2;
  __hip_bfloat16* Wo_bf   = (__hip_bfloat16*)p; p += (size_t)DMODEL * NH * HD * 2;
  __hip_bfloat16* Q_bf    = (__hip_bfloat16*)p; p += (size_t)NB * S_LEN * NH * HD * 2;
  __hip_bfloat16* K_bf    = (__hip_bfloat16*)p; p += (size_t)NB * S_LEN * NKVH * HD * 2;
  __hip_bfloat16* Vt_bf   = (__hip_bfloat16*)p; p += (size_t)NB * NKVH * HD * S_LEN * 2;
  __hip_bfloat16* attn_bf = (__hip_bfloat16*)p; p += (size_t)NB * S_LEN * NH * HD * 2;

  auto cvt = [&](const float* src, __hip_bfloat16* dst, size_t n) {
    int n4 = (int)(n / 4);
    cvt_kernel<<<(n4 + 255) / 256, 256, 0, stream>>>(src, dst, n4);
  };
  cvt(x,  x_bf,  (size_t)NB * S_LEN * DMODEL);
  cvt(Wq, Wq_bf, (size_t)NH * HD * DMODEL);
  cvt(Wk, Wk_bf, (size_t)NKVH * HD * DMODEL);
  cvt(Wv, Wv_bf, (size_t)NKVH * HD * DMODEL);
  cvt(Wo, Wo_bf, (size_t)DMODEL * NH * HD);

  const dim3 blk(256);
  // fused QKV projection + RoPE (virtual N = 2048 + 512 + 512 = 3072)
  gemm_qkv<<<dim3(3072 / 128, (NB * S_LEN) / 128), blk, 0, stream>>>(
      x_bf, Wq_bf, Wk_bf, Wv_bf, Q_bf, K_bf, Vt_bf, cosb, sinb);

  attn_kernel<<<dim3(S_LEN / 64, NB * NH), blk, 0, stream>>>(Q_bf, K_bf, Vt_bf, attn_bf);

  // output projection -> fp32 d_out
  gemm_o<<<dim3(DMODEL / 128, (NB * S_LEN) / 128), blk, 0, stream>>>(attn_bf, Wo_bf, out);
}

// Round 5
// 410.933 us; speedup vs baseline: 1.3908x; 1.0013x over previous
//
#include <hip/hip_runtime.h>
#include <hip/hip_bf16.h>

typedef __attribute__((ext_vector_type(8))) short bf16x8_t;   // 8 bf16 = 4 VGPRs (MFMA A/B frag)
typedef __attribute__((ext_vector_type(4))) float f32x4;      // MFMA C/D frag

#define S_LEN  2048
#define NB     2
#define NH     32
#define NKVH   8
#define HD     64
#define DMODEL 2048
#define SCALE  0.125f

// async global->LDS, 16B per lane; lds dst is wave-uniform base + lane*16
__device__ __forceinline__ void gload16(const __hip_bfloat16* g, __hip_bfloat16* l) {
  __builtin_amdgcn_global_load_lds(
      (const __attribute__((address_space(1))) void*)g,
      (__attribute__((address_space(3))) void*)l, 16, 0, 0);
}

// ---------------------------------------------------------------- fused fp32 -> bf16 (5 segments)
struct CvtSeg { const float* src; __hip_bfloat16* dst; int n4; };
struct CvtArgs { CvtSeg s[5]; };

__global__ __launch_bounds__(256) void cvt_all(CvtArgs a) {
  int i = blockIdx.x * blockDim.x + threadIdx.x;
#pragma unroll
  for (int k = 0; k < 5; ++k) {
    if (i < a.s[k].n4) {
      float4 v = ((const float4*)a.s[k].src)[i];
      __hip_bfloat16 o0 = __float2bfloat16(v.x), o1 = __float2bfloat16(v.y);
      __hip_bfloat16 o2 = __float2bfloat16(v.z), o3 = __float2bfloat16(v.w);
      ushort4 pk;
      pk.x = *(unsigned short*)&o0; pk.y = *(unsigned short*)&o1;
      pk.z = *(unsigned short*)&o2; pk.w = *(unsigned short*)&o3;
      ((ushort4*)a.s[k].dst)[i] = pk;
      return;
    }
    i -= a.s[k].n4;
  }
}

// ---------------------------------------------------------------- fused QKV projection + RoPE (2-phase dbuf)
__global__ __launch_bounds__(256)
void gemm_qkv(const __hip_bfloat16* __restrict__ A,
              const __hip_bfloat16* __restrict__ Wq,
              const __hip_bfloat16* __restrict__ Wk,
              const __hip_bfloat16* __restrict__ Wv,
              __hip_bfloat16* __restrict__ Qo,
              __hip_bfloat16* __restrict__ Ko,
              __hip_bfloat16* __restrict__ Vto,
              const float* __restrict__ cosb,
              const float* __restrict__ sinb)
{
  __shared__ __align__(16) __hip_bfloat16 As[2][128][32];
  __shared__ __align__(16) __hip_bfloat16 Bs[2][128][32];
  const int K = DMODEL;

  const int tid  = threadIdx.x;
  const int lane = tid & 63;
  const int w    = tid >> 6;
  const int wr   = (w >> 1) * 64;
  const int wc   = (w & 1) * 64;
  const int brow = blockIdx.y * 128;
  const int fr   = lane & 15;
  const int fg   = lane >> 4;

  const int bc = blockIdx.x * 128;
  const __hip_bfloat16* Bt; int bcol; int path;
  if (bc < 2048)      { Bt = Wq; bcol = bc;        path = 0; }
  else if (bc < 2560) { Bt = Wk; bcol = bc - 2048; path = 1; }
  else                { Bt = Wv; bcol = bc - 2560; path = 2; }

  const f32x4 fz = {0.f, 0.f, 0.f, 0.f};
  f32x4 acc[4][4];
#pragma unroll
  for (int i = 0; i < 4; ++i)
#pragma unroll
    for (int j = 0; j < 4; ++j) acc[i][j] = fz;

  const int lrow = lane >> 2;           // 0..15
  const int lcol = (lane & 3) * 8;      // 16B chunk
  const __hip_bfloat16* Ag = A  + (size_t)(brow + w * 32 + lrow) * K + lcol;
  const __hip_bfloat16* Bg = Bt + (size_t)(bcol + w * 32 + lrow) * K + lcol;

  auto stage = [&](int buf, int kt) {
    gload16(Ag + kt,                    &As[buf][w * 32][0]);
    gload16(Ag + (size_t)16 * K + kt,   &As[buf][w * 32 + 16][0]);
    gload16(Bg + kt,                    &Bs[buf][w * 32][0]);
    gload16(Bg + (size_t)16 * K + kt,   &Bs[buf][w * 32 + 16][0]);
  };

  stage(0, 0);
  __syncthreads();
  int cur = 0;
  for (int kt = 0; kt < K; kt += 32) {
    if (kt + 32 < K) stage(cur ^ 1, kt + 32);

    bf16x8_t af[4], bfr[4];
#pragma unroll
    for (int mi = 0; mi < 4; ++mi)
      af[mi] = *(const bf16x8_t*)&As[cur][wr + mi * 16 + fr][fg * 8];
#pragma unroll
    for (int ni = 0; ni < 4; ++ni)
      bfr[ni] = *(const bf16x8_t*)&Bs[cur][wc + ni * 16 + fr][fg * 8];
#pragma unroll
    for (int mi = 0; mi < 4; ++mi)
#pragma unroll
      for (int ni = 0; ni < 4; ++ni)
        acc[mi][ni] = __builtin_amdgcn_mfma_f32_16x16x32_bf16(af[mi], bfr[ni], acc[mi][ni], 0, 0, 0);

    __syncthreads();
    cur ^= 1;
  }

  if (path == 2) {
#pragma unroll
    for (int mi = 0; mi < 4; ++mi) {
#pragma unroll
      for (int ni = 0; ni < 4; ++ni) {
        const int row0 = brow + wr + mi * 16 + fg * 4;
        const int col  = bcol + wc + ni * 16 + fr;
        const int b = row0 >> 11, s = row0 & 2047;
        const int kvh = col >> 6, d = col & 63;
        __hip_bfloat16 v0 = __float2bfloat16(acc[mi][ni][0]);
        __hip_bfloat16 v1 = __float2bfloat16(acc[mi][ni][1]);
        __hip_bfloat16 v2 = __float2bfloat16(acc[mi][ni][2]);
        __hip_bfloat16 v3 = __float2bfloat16(acc[mi][ni][3]);
        ushort4 pk;
        pk.x = *(unsigned short*)&v0; pk.y = *(unsigned short*)&v1;
        pk.z = *(unsigned short*)&v2; pk.w = *(unsigned short*)&v3;
        *(ushort4*)&Vto[(((size_t)b * NKVH + kvh) * HD + d) * S_LEN + s] = pk;
      }
    }
  } else {
    __hip_bfloat16* C = (path == 0) ? Qo : Ko;
    const int N = (path == 0) ? (NH * HD) : (NKVH * HD);
#pragma unroll
    for (int mi = 0; mi < 4; ++mi) {
#pragma unroll
      for (int r = 0; r < 4; ++r) {
        const int row = brow + wr + mi * 16 + fg * 4 + r;
#pragma unroll
        for (int ni = 0; ni < 2; ++ni) {   // ni pairs with ni+2 : (d, d+32) same head, same lane
          const int colL = bcol + wc + ni * 16 + fr;
          const int d    = (colL & 63);    // < 32
          const float c  = cosb[(size_t)row * HD + d];
          const float sn = sinb[(size_t)row * HD + d];
          const float v0 = acc[mi][ni][r];
          const float v1 = acc[mi][ni + 2][r];
          C[(size_t)row * N + colL]      = __float2bfloat16(v0 * c - v1 * sn);
          C[(size_t)row * N + colL + 32] = __float2bfloat16(v1 * c + v0 * sn);
        }
      }
    }
  }
}

// ---------------------------------------------------------------- output projection (2-phase dbuf, fp32 out)
__global__ __launch_bounds__(256)
void gemm_o(const __hip_bfloat16* __restrict__ A,
            const __hip_bfloat16* __restrict__ Bt,
            float* __restrict__ C)
{
  __shared__ __align__(16) __hip_bfloat16 As[2][128][32];
  __shared__ __align__(16) __hip_bfloat16 Bs[2][128][32];
  const int K = DMODEL, N = DMODEL;

  const int tid  = threadIdx.x;
  const int lane = tid & 63;
  const int w    = tid >> 6;
  const int wr   = (w >> 1) * 64;
  const int wc   = (w & 1) * 64;
  const int brow = blockIdx.y * 128;
  const int bcol = blockIdx.x * 128;
  const int fr   = lane & 15;
  const int fg   = lane >> 4;

  const f32x4 fz = {0.f, 0.f, 0.f, 0.f};
  f32x4 acc[4][4];
#pragma unroll
  for (int i = 0; i < 4; ++i)
#pragma unroll
    for (int j = 0; j < 4; ++j) acc[i][j] = fz;

  const int lrow = lane >> 2;
  const int lcol = (lane & 3) * 8;
  const __hip_bfloat16* Ag = A  + (size_t)(brow + w * 32 + lrow) * K + lcol;
  const __hip_bfloat16* Bg = Bt + (size_t)(bcol + w * 32 + lrow) * K + lcol;

  auto stage = [&](int buf, int kt) {
    gload16(Ag + kt,                  &As[buf][w * 32][0]);
    gload16(Ag + (size_t)16 * K + kt, &As[buf][w * 32 + 16][0]);
    gload16(Bg + kt,                  &Bs[buf][w * 32][0]);
    gload16(Bg + (size_t)16 * K + kt, &Bs[buf][w * 32 + 16][0]);
  };

  stage(0, 0);
  __syncthreads();
  int cur = 0;
  for (int kt = 0; kt < K; kt += 32) {
    if (kt + 32 < K) stage(cur ^ 1, kt + 32);

    bf16x8_t af[4], bfr[4];
#pragma unroll
    for (int mi = 0; mi < 4; ++mi)
      af[mi] = *(const bf16x8_t*)&As[cur][wr + mi * 16 + fr][fg * 8];
#pragma unroll
    for (int ni = 0; ni < 4; ++ni)
      bfr[ni] = *(const bf16x8_t*)&Bs[cur][wc + ni * 16 + fr][fg * 8];
#pragma unroll
    for (int mi = 0; mi < 4; ++mi)
#pragma unroll
      for (int ni = 0; ni < 4; ++ni)
        acc[mi][ni] = __builtin_amdgcn_mfma_f32_16x16x32_bf16(af[mi], bfr[ni], acc[mi][ni], 0, 0, 0);

    __syncthreads();
    cur ^= 1;
  }

#pragma unroll
  for (int mi = 0; mi < 4; ++mi)
#pragma unroll
    for (int ni = 0; ni < 4; ++ni) {
      const int row0 = brow + wr + mi * 16 + fg * 4;
      const int col  = bcol + wc + ni * 16 + fr;
#pragma unroll
      for (int r = 0; r < 4; ++r)
        C[(size_t)(row0 + r) * N + col] = acc[mi][ni][r];
    }
}

// ---------------------------------------------------------------- flash attention (causal, GQA)
// QBLK=128 (4 waves x 32 q-rows), KVBLK=64, 2-phase double-buffered K/V via global_load_lds.
// LDS K/V layout: linear [64][64] bf16, XOR-swizzled 16B slots: slot = chunk ^ (row&7),
// achieved by pre-swizzling the per-lane GLOBAL source address (involution; rule 21).
__global__ __launch_bounds__(256)
void attn_kernel(const __hip_bfloat16* __restrict__ Q, const __hip_bfloat16* __restrict__ K,
                 const __hip_bfloat16* __restrict__ Vt, __hip_bfloat16* __restrict__ O)
{
  __shared__ __align__(16) __hip_bfloat16 Ks[2][64][64];
  __shared__ __align__(16) __hip_bfloat16 Vs[2][64][64];
  __shared__ __align__(16) __hip_bfloat16 Ps[4][2][16][72];   // per-wave P, padded

  const int lane = threadIdx.x & 63;
  const int w    = threadIdx.x >> 6;
  const int fr   = lane & 15;
  const int fg   = lane >> 4;
  const int r8   = lane >> 3;      // stage: row within 8-row chunk
  const int j8   = lane & 7;       // stage: 16B slot within row
  const int bh   = blockIdx.y;
  const int b    = bh >> 5;
  const int h    = bh & 31;
  const int kvh  = h >> 2;
  const int qt    = gridDim.x - 1 - blockIdx.x;   // LPT: heavy blocks first
  const int qbase = qt * 128;

  const __hip_bfloat16* Qg = Q + ((size_t)(b * S_LEN + qbase)) * DMODEL + h * HD;
  const __hip_bfloat16* Kg = K + (size_t)b * S_LEN * (NKVH * HD) + kvh * HD;
  const __hip_bfloat16* Vg = Vt + ((size_t)(b * NKVH + kvh)) * HD * S_LEN;

  // Q fragments: 2 subtiles x 16 q-rows x 64 feat per wave (B-operand, col q = fr)
  bf16x8_t qf[2][2];
#pragma unroll
  for (int s = 0; s < 2; ++s)
#pragma unroll
    for (int kk = 0; kk < 2; ++kk)
      qf[s][kk] = *(const bf16x8_t*)(Qg + (size_t)(w * 32 + s * 16 + fr) * DMODEL + kk * 32 + fg * 8);

  const f32x4 fz = {0.f, 0.f, 0.f, 0.f};
  f32x4 acc[2][4];
#pragma unroll
  for (int s = 0; s < 2; ++s)
#pragma unroll
    for (int i = 0; i < 4; ++i) acc[s][i] = fz;
  float m_[2] = {-1e30f, -1e30f}, l_[2] = {0.f, 0.f};

  // wave w stages K rows [w*16, w*16+16) and V rows [w*16, w*16+16); source pre-swizzled
  auto stage = [&](int buf, int kt) {
#pragma unroll
    for (int half = 0; half < 2; ++half) {
      const int row = w * 16 + half * 8 + r8;      // row&7 == r8
      gload16(Kg + (size_t)(kt + row) * (NKVH * HD) + (j8 ^ r8) * 8, &Ks[buf][w * 16 + half * 8][0]);
      gload16(Vg + (size_t)row * S_LEN + kt + (j8 ^ r8) * 8,         &Vs[buf][w * 16 + half * 8][0]);
    }
  };
  auto ldK = [&](int buf, int row, int cidx) -> bf16x8_t {
    return *(const bf16x8_t*)&Ks[buf][row][(cidx ^ (row & 7)) * 8];
  };
  auto ldV = [&](int buf, int row, int cidx) -> bf16x8_t {
    return *(const bf16x8_t*)&Vs[buf][row][(cidx ^ (row & 7)) * 8];
  };

  stage(0, 0);
  __syncthreads();
  int cur = 0;
  const int NT = 2 * qt + 2;
  for (int t = 0; t < NT; ++t) {
    const int kt = t * 64;
    if (t + 1 < NT) stage(cur ^ 1, kt + 64);   // prefetch overlaps this tile's compute

    // QK^T swapped: rows = keys, col = q = fr; K frags shared by both subtiles
    f32x4 sc[2][4];
#pragma unroll
    for (int c = 0; c < 4; ++c) {
      const int krow = c * 16 + fr;
      bf16x8_t k0 = ldK(cur, krow, fg);
      bf16x8_t k1 = ldK(cur, krow, 4 + fg);
      sc[0][c] = __builtin_amdgcn_mfma_f32_16x16x32_bf16(k0, qf[0][0], fz, 0, 0, 0);
      sc[0][c] = __builtin_amdgcn_mfma_f32_16x16x32_bf16(k1, qf[0][1], sc[0][c], 0, 0, 0);
      sc[1][c] = __builtin_amdgcn_mfma_f32_16x16x32_bf16(k0, qf[1][0], fz, 0, 0, 0);
      sc[1][c] = __builtin_amdgcn_mfma_f32_16x16x32_bf16(k1, qf[1][1], sc[1][c], 0, 0, 0);
    }

    // online softmax per subtile (lane owns q = fr); mask only when tile crosses diagonal
#pragma unroll
    for (int s = 0; s < 2; ++s) {
      const int base_s = qbase + w * 32 + s * 16;
      float p[4][4];
      float tm = -1e30f;
      if (kt + 63 > base_s) {
#pragma unroll
        for (int c = 0; c < 4; ++c)
#pragma unroll
          for (int r = 0; r < 4; ++r) {
            float v = sc[s][c][r] * SCALE;
            if (kt + c * 16 + fg * 4 + r > base_s + fr) v = -1e30f;
            p[c][r] = v; tm = fmaxf(tm, v);
          }
      } else {
#pragma unroll
        for (int c = 0; c < 4; ++c)
#pragma unroll
          for (int r = 0; r < 4; ++r) {
            float v = sc[s][c][r] * SCALE;
            p[c][r] = v; tm = fmaxf(tm, v);
          }
      }
      tm = fmaxf(tm, __shfl_xor(tm, 16));
      tm = fmaxf(tm, __shfl_xor(tm, 32));

      const float mnew = fmaxf(m_[s], tm);
      const float sf = __expf(m_[s] - mnew);
      m_[s] = mnew;

      float ts = 0.f;
#pragma unroll
      for (int c = 0; c < 4; ++c)
#pragma unroll
        for (int r = 0; r < 4; ++r) { p[c][r] = __expf(p[c][r] - mnew); ts += p[c][r]; }
      ts += __shfl_xor(ts, 16);
      ts += __shfl_xor(ts, 32);
      l_[s] = l_[s] * sf + ts;

      float sfv[4];
#pragma unroll
      for (int r = 0; r < 4; ++r) sfv[r] = __shfl(sf, fg * 4 + r);
#pragma unroll
      for (int fc = 0; fc < 4; ++fc)
#pragma unroll
        for (int r = 0; r < 4; ++r) acc[s][fc][r] *= sfv[r];

      // P -> per-wave LDS [q][key], 8B packed stores
#pragma unroll
      for (int c = 0; c < 4; ++c) {
        __hip_bfloat16 b0 = __float2bfloat16(p[c][0]);
        __hip_bfloat16 b1 = __float2bfloat16(p[c][1]);
        __hip_bfloat16 b2 = __float2bfloat16(p[c][2]);
        __hip_bfloat16 b3 = __float2bfloat16(p[c][3]);
        ushort4 pk;
        pk.x = *(unsigned short*)&b0; pk.y = *(unsigned short*)&b1;
        pk.z = *(unsigned short*)&b2; pk.w = *(unsigned short*)&b3;
        *(ushort4*)&Ps[w][s][fr][c * 16 + fg * 4] = pk;
      }
    }

    // PV: A = P (row q = fr), B = V (col d = fr); V frags shared by both subtiles
#pragma unroll
    for (int kk = 0; kk < 2; ++kk) {
      bf16x8_t pa0 = *(const bf16x8_t*)&Ps[w][0][fr][kk * 32 + fg * 8];
      bf16x8_t pa1 = *(const bf16x8_t*)&Ps[w][1][fr][kk * 32 + fg * 8];
#pragma unroll
      for (int fc = 0; fc < 4; ++fc) {
        bf16x8_t vf = ldV(cur, fc * 16 + fr, kk * 4 + fg);
        acc[0][fc] = __builtin_amdgcn_mfma_f32_16x16x32_bf16(pa0, vf, acc[0][fc], 0, 0, 0);
        acc[1][fc] = __builtin_amdgcn_mfma_f32_16x16x32_bf16(pa1, vf, acc[1][fc], 0, 0, 0);
      }
    }

    __syncthreads();   // prefetch landed (auto vmcnt/lgkm drain); all waves done with buf[cur]
    cur ^= 1;
  }

  // epilogue: acc row q_local = fg*4+r, col d = fc*16+fr; l lives at lane q_local
  float lv[2][4];
#pragma unroll
  for (int s = 0; s < 2; ++s)
#pragma unroll
    for (int r = 0; r < 4; ++r)
      lv[s][r] = __builtin_amdgcn_rcpf(__shfl(l_[s], fg * 4 + r));
#pragma unroll
  for (int s = 0; s < 2; ++s)
#pragma unroll
    for (int fc = 0; fc < 4; ++fc)
#pragma unroll
      for (int r = 0; r < 4; ++r) {
        const size_t row = (size_t)(b * S_LEN + qbase + w * 32 + s * 16 + fg * 4 + r);
        O[row * DMODEL + h * HD + fc * 16 + fr] = __float2bfloat16(acc[s][fc][r] * lv[s][r]);
      }
}

// ---------------------------------------------------------------- launch
extern "C" void kernel_launch(void* const* d_in, const int* in_sizes, int n_in,
                              void* d_out, int out_size, void* d_ws, size_t ws_size,
                              hipStream_t stream)
{
  const float* x    = (const float*)d_in[0];
  const float* cosb = (const float*)d_in[1];
  const float* sinb = (const float*)d_in[2];
  const float* Wq   = (const float*)d_in[3];
  const float* Wk   = (const float*)d_in[4];
  const float* Wv   = (const float*)d_in[5];
  const float* Wo   = (const float*)d_in[6];
  float* out = (float*)d_out;

  char* p = (char*)d_ws;
  __hip_bfloat16* x_bf    = (__hip_bfloat16*)p; p += (size_t)NB * S_LEN * DMODEL * 2;
  __hip_bfloat16* Wq_bf   = (__hip_bfloat16*)p; p += (size_t)NH * HD * DMODEL * 2;
  __hip_bfloat16* Wk_bf   = (__hip_bfloat16*)p; p += (size_t)NKVH * HD * DMODEL * 2;
  __hip_bfloat16* Wv_bf   = (__hip_bfloat16*)p; p += (size_t)NKVH * HD * DMODEL * 2;
  __hip_bfloat16* Wo_bf   = (__hip_bfloat16*)p; p += (size_t)DMODEL * NH * HD * 2;
  __hip_bfloat16* Q_bf    = (__hip_bfloat16*)p; p += (size_t)NB * S_LEN * NH * HD * 2;
  __hip_bfloat16* K_bf    = (__hip_bfloat16*)p; p += (size_t)NB * S_LEN * NKVH * HD * 2;
  __hip_bfloat16* Vt_bf   = (__hip_bfloat16*)p; p += (size_t)NB * NKVH * HD * S_LEN * 2;
  __hip_bfloat16* attn_bf = (__hip_bfloat16*)p; p += (size_t)NB * S_LEN * NH * HD * 2;

  CvtArgs ca;
  ca.s[0] = { x,  x_bf,  (int)((size_t)NB * S_LEN * DMODEL / 4) };
  ca.s[1] = { Wq, Wq_bf, (int)((size_t)NH * HD * DMODEL / 4) };
  ca.s[2] = { Wk, Wk_bf, (int)((size_t)NKVH * HD * DMODEL / 4) };
  ca.s[3] = { Wv, Wv_bf, (int)((size_t)NKVH * HD * DMODEL / 4) };
  ca.s[4] = { Wo, Wo_bf, (int)((size_t)DMODEL * NH * HD / 4) };
  int total4 = ca.s[0].n4 + ca.s[1].n4 + ca.s[2].n4 + ca.s[3].n4 + ca.s[4].n4;
  cvt_all<<<(total4 + 255) / 256, 256, 0, stream>>>(ca);

  const dim3 blk(256);
  gemm_qkv<<<dim3(3072 / 128, (NB * S_LEN) / 128), blk, 0, stream>>>(
      x_bf, Wq_bf, Wk_bf, Wv_bf, Q_bf, K_bf, Vt_bf, cosb, sinb);

  attn_kernel<<<dim3(S_LEN / 128, NB * NH), blk, 0, stream>>>(Q_bf, K_bf, Vt_bf, attn_bf);

  gemm_o<<<dim3(DMODEL / 128, (NB * S_LEN) / 128), blk, 0, stream>>>(attn_bf, Wo_bf, out);
}

// Round 6
// 377.319 us; speedup vs baseline: 1.5147x; 1.0891x over previous
//
#include <hip/hip_runtime.h>
#include <hip/hip_bf16.h>

typedef __attribute__((ext_vector_type(8))) short bf16x8_t;   // 8 bf16 = 4 VGPRs (MFMA A/B frag)
typedef __attribute__((ext_vector_type(4))) float f32x4;      // MFMA C/D frag

#define S_LEN  2048
#define NB     2
#define NH     32
#define NKVH   8
#define HD     64
#define DMODEL 2048
#define SCALE  0.125f
#define CEXP   0.18033688f     // SCALE * log2(e)
#define THRRAW 44.0f           // defer-max threshold in raw-logit units (~8 exp2 units)

// async global->LDS, 16B per lane; lds dst is wave-uniform base + lane*16
__device__ __forceinline__ void gload16(const __hip_bfloat16* g, __hip_bfloat16* l) {
  __builtin_amdgcn_global_load_lds(
      (const __attribute__((address_space(1))) void*)g,
      (__attribute__((address_space(3))) void*)l, 16, 0, 0);
}

// ---------------------------------------------------------------- fused fp32 -> bf16 (5 segments)
struct CvtSeg { const float* src; __hip_bfloat16* dst; int n4; };
struct CvtArgs { CvtSeg s[5]; };

__global__ __launch_bounds__(256) void cvt_all(CvtArgs a) {
  int i = blockIdx.x * blockDim.x + threadIdx.x;
#pragma unroll
  for (int k = 0; k < 5; ++k) {
    if (i < a.s[k].n4) {
      float4 v = ((const float4*)a.s[k].src)[i];
      __hip_bfloat16 o0 = __float2bfloat16(v.x), o1 = __float2bfloat16(v.y);
      __hip_bfloat16 o2 = __float2bfloat16(v.z), o3 = __float2bfloat16(v.w);
      ushort4 pk;
      pk.x = *(unsigned short*)&o0; pk.y = *(unsigned short*)&o1;
      pk.z = *(unsigned short*)&o2; pk.w = *(unsigned short*)&o3;
      ((ushort4*)a.s[k].dst)[i] = pk;
      return;
    }
    i -= a.s[k].n4;
  }
}

// ---------------------------------------------------------------- fused QKV projection + RoPE (2-phase dbuf)
__global__ __launch_bounds__(256)
void gemm_qkv(const __hip_bfloat16* __restrict__ A,
              const __hip_bfloat16* __restrict__ Wq,
              const __hip_bfloat16* __restrict__ Wk,
              const __hip_bfloat16* __restrict__ Wv,
              __hip_bfloat16* __restrict__ Qo,
              __hip_bfloat16* __restrict__ Ko,
              __hip_bfloat16* __restrict__ Vto,
              const float* __restrict__ cosb,
              const float* __restrict__ sinb)
{
  __shared__ __align__(16) __hip_bfloat16 As[2][128][32];
  __shared__ __align__(16) __hip_bfloat16 Bs[2][128][32];
  const int K = DMODEL;

  const int tid  = threadIdx.x;
  const int lane = tid & 63;
  const int w    = tid >> 6;
  const int wr   = (w >> 1) * 64;
  const int wc   = (w & 1) * 64;
  const int brow = blockIdx.y * 128;
  const int fr   = lane & 15;
  const int fg   = lane >> 4;

  const int bc = blockIdx.x * 128;
  const __hip_bfloat16* Bt; int bcol; int path;
  if (bc < 2048)      { Bt = Wq; bcol = bc;        path = 0; }
  else if (bc < 2560) { Bt = Wk; bcol = bc - 2048; path = 1; }
  else                { Bt = Wv; bcol = bc - 2560; path = 2; }

  const f32x4 fz = {0.f, 0.f, 0.f, 0.f};
  f32x4 acc[4][4];
#pragma unroll
  for (int i = 0; i < 4; ++i)
#pragma unroll
    for (int j = 0; j < 4; ++j) acc[i][j] = fz;

  const int lrow = lane >> 2;           // 0..15
  const int lcol = (lane & 3) * 8;      // 16B chunk
  const __hip_bfloat16* Ag = A  + (size_t)(brow + w * 32 + lrow) * K + lcol;
  const __hip_bfloat16* Bg = Bt + (size_t)(bcol + w * 32 + lrow) * K + lcol;

  auto stage = [&](int buf, int kt) {
    gload16(Ag + kt,                    &As[buf][w * 32][0]);
    gload16(Ag + (size_t)16 * K + kt,   &As[buf][w * 32 + 16][0]);
    gload16(Bg + kt,                    &Bs[buf][w * 32][0]);
    gload16(Bg + (size_t)16 * K + kt,   &Bs[buf][w * 32 + 16][0]);
  };

  stage(0, 0);
  __syncthreads();
  int cur = 0;
  for (int kt = 0; kt < K; kt += 32) {
    if (kt + 32 < K) stage(cur ^ 1, kt + 32);

    bf16x8_t af[4], bfr[4];
#pragma unroll
    for (int mi = 0; mi < 4; ++mi)
      af[mi] = *(const bf16x8_t*)&As[cur][wr + mi * 16 + fr][fg * 8];
#pragma unroll
    for (int ni = 0; ni < 4; ++ni)
      bfr[ni] = *(const bf16x8_t*)&Bs[cur][wc + ni * 16 + fr][fg * 8];
#pragma unroll
    for (int mi = 0; mi < 4; ++mi)
#pragma unroll
      for (int ni = 0; ni < 4; ++ni)
        acc[mi][ni] = __builtin_amdgcn_mfma_f32_16x16x32_bf16(af[mi], bfr[ni], acc[mi][ni], 0, 0, 0);

    __syncthreads();
    cur ^= 1;
  }

  if (path == 2) {
#pragma unroll
    for (int mi = 0; mi < 4; ++mi) {
#pragma unroll
      for (int ni = 0; ni < 4; ++ni) {
        const int row0 = brow + wr + mi * 16 + fg * 4;
        const int col  = bcol + wc + ni * 16 + fr;
        const int b = row0 >> 11, s = row0 & 2047;
        const int kvh = col >> 6, d = col & 63;
        __hip_bfloat16 v0 = __float2bfloat16(acc[mi][ni][0]);
        __hip_bfloat16 v1 = __float2bfloat16(acc[mi][ni][1]);
        __hip_bfloat16 v2 = __float2bfloat16(acc[mi][ni][2]);
        __hip_bfloat16 v3 = __float2bfloat16(acc[mi][ni][3]);
        ushort4 pk;
        pk.x = *(unsigned short*)&v0; pk.y = *(unsigned short*)&v1;
        pk.z = *(unsigned short*)&v2; pk.w = *(unsigned short*)&v3;
        *(ushort4*)&Vto[(((size_t)b * NKVH + kvh) * HD + d) * S_LEN + s] = pk;
      }
    }
  } else {
    __hip_bfloat16* C = (path == 0) ? Qo : Ko;
    const int N = (path == 0) ? (NH * HD) : (NKVH * HD);
#pragma unroll
    for (int mi = 0; mi < 4; ++mi) {
#pragma unroll
      for (int r = 0; r < 4; ++r) {
        const int row = brow + wr + mi * 16 + fg * 4 + r;
#pragma unroll
        for (int ni = 0; ni < 2; ++ni) {   // ni pairs with ni+2 : (d, d+32) same head, same lane
          const int colL = bcol + wc + ni * 16 + fr;
          const int d    = (colL & 63);    // < 32
          const float c  = cosb[(size_t)row * HD + d];
          const float sn = sinb[(size_t)row * HD + d];
          const float v0 = acc[mi][ni][r];
          const float v1 = acc[mi][ni + 2][r];
          C[(size_t)row * N + colL]      = __float2bfloat16(v0 * c - v1 * sn);
          C[(size_t)row * N + colL + 32] = __float2bfloat16(v1 * c + v0 * sn);
        }
      }
    }
  }
}

// ---------------------------------------------------------------- output projection (2-phase dbuf, fp32 out)
__global__ __launch_bounds__(256)
void gemm_o(const __hip_bfloat16* __restrict__ A,
            const __hip_bfloat16* __restrict__ Bt,
            float* __restrict__ C)
{
  __shared__ __align__(16) __hip_bfloat16 As[2][128][32];
  __shared__ __align__(16) __hip_bfloat16 Bs[2][128][32];
  const int K = DMODEL, N = DMODEL;

  const int tid  = threadIdx.x;
  const int lane = tid & 63;
  const int w    = tid >> 6;
  const int wr   = (w >> 1) * 64;
  const int wc   = (w & 1) * 64;
  const int brow = blockIdx.y * 128;
  const int bcol = blockIdx.x * 128;
  const int fr   = lane & 15;
  const int fg   = lane >> 4;

  const f32x4 fz = {0.f, 0.f, 0.f, 0.f};
  f32x4 acc[4][4];
#pragma unroll
  for (int i = 0; i < 4; ++i)
#pragma unroll
    for (int j = 0; j < 4; ++j) acc[i][j] = fz;

  const int lrow = lane >> 2;
  const int lcol = (lane & 3) * 8;
  const __hip_bfloat16* Ag = A  + (size_t)(brow + w * 32 + lrow) * K + lcol;
  const __hip_bfloat16* Bg = Bt + (size_t)(bcol + w * 32 + lrow) * K + lcol;

  auto stage = [&](int buf, int kt) {
    gload16(Ag + kt,                  &As[buf][w * 32][0]);
    gload16(Ag + (size_t)16 * K + kt, &As[buf][w * 32 + 16][0]);
    gload16(Bg + kt,                  &Bs[buf][w * 32][0]);
    gload16(Bg + (size_t)16 * K + kt, &Bs[buf][w * 32 + 16][0]);
  };

  stage(0, 0);
  __syncthreads();
  int cur = 0;
  for (int kt = 0; kt < K; kt += 32) {
    if (kt + 32 < K) stage(cur ^ 1, kt + 32);

    bf16x8_t af[4], bfr[4];
#pragma unroll
    for (int mi = 0; mi < 4; ++mi)
      af[mi] = *(const bf16x8_t*)&As[cur][wr + mi * 16 + fr][fg * 8];
#pragma unroll
    for (int ni = 0; ni < 4; ++ni)
      bfr[ni] = *(const bf16x8_t*)&Bs[cur][wc + ni * 16 + fr][fg * 8];
#pragma unroll
    for (int mi = 0; mi < 4; ++mi)
#pragma unroll
      for (int ni = 0; ni < 4; ++ni)
        acc[mi][ni] = __builtin_amdgcn_mfma_f32_16x16x32_bf16(af[mi], bfr[ni], acc[mi][ni], 0, 0, 0);

    __syncthreads();
    cur ^= 1;
  }

#pragma unroll
  for (int mi = 0; mi < 4; ++mi)
#pragma unroll
    for (int ni = 0; ni < 4; ++ni) {
      const int row0 = brow + wr + mi * 16 + fg * 4;
      const int col  = bcol + wc + ni * 16 + fr;
#pragma unroll
      for (int r = 0; r < 4; ++r)
        C[(size_t)(row0 + r) * N + col] = acc[mi][ni][r];
    }
}

// ---------------------------------------------------------------- flash attention (causal, GQA)
// QBLK=128, 8 waves x 16 q-rows (512 threads). KVBLK=64, dbuf K/V via global_load_lds,
// XOR-swizzled via pre-swizzled global source (rule 21). 1 barrier/tile.
// Softmax diet: raw-domain max + fused scale in exp2, defer-max rescale (T13),
// per-lane partial l with epilogue reduce, fully-masked wave-tiles skipped.
__global__ __launch_bounds__(512, 6)
void attn_kernel(const __hip_bfloat16* __restrict__ Q, const __hip_bfloat16* __restrict__ K,
                 const __hip_bfloat16* __restrict__ Vt, __hip_bfloat16* __restrict__ O)
{
  __shared__ __align__(16) __hip_bfloat16 Ks[2][64][64];
  __shared__ __align__(16) __hip_bfloat16 Vs[2][64][64];
  __shared__ __align__(16) __hip_bfloat16 Ps[8][16][72];   // per-wave P, padded

  const int lane = threadIdx.x & 63;
  const int w    = threadIdx.x >> 6;       // 0..7
  const int fr   = lane & 15;
  const int fg   = lane >> 4;
  const int r8   = lane >> 3;              // stage: row within 8-row chunk
  const int j8   = lane & 7;               // stage: 16B slot within row
  const int bh   = blockIdx.y;
  const int b    = bh >> 5;
  const int h    = bh & 31;
  const int kvh  = h >> 2;
  const int qt    = gridDim.x - 1 - blockIdx.x;   // LPT: heavy blocks first
  const int qbase = qt * 128;
  const int base_s = qbase + w * 16;       // this wave's first q-row

  const __hip_bfloat16* Qg = Q + ((size_t)(b * S_LEN + qbase)) * DMODEL + h * HD;
  const __hip_bfloat16* Kg = K + (size_t)b * S_LEN * (NKVH * HD) + kvh * HD;
  const __hip_bfloat16* Vg = Vt + ((size_t)(b * NKVH + kvh)) * HD * S_LEN;

  // Q fragments: 16 q-rows x 64 feat per wave (B-operand, col q = fr)
  bf16x8_t qf[2];
#pragma unroll
  for (int kk = 0; kk < 2; ++kk)
    qf[kk] = *(const bf16x8_t*)(Qg + (size_t)(w * 16 + fr) * DMODEL + kk * 32 + fg * 8);

  const f32x4 fz = {0.f, 0.f, 0.f, 0.f};
  f32x4 acc[4];
#pragma unroll
  for (int i = 0; i < 4; ++i) acc[i] = fz;
  float m_ = -1e30f;     // raw-logit running max (uniform across the 4 fg lanes of q=fr)
  float l_ = 0.f;        // PER-LANE partial sum; reduced across fg in epilogue

  // waves 0-3 stage K rows, waves 4-7 stage V rows; source pre-swizzled (chunk j8^r8)
  auto stage = [&](int buf, int kt) {
    const int rb = (w & 3) * 16;
    if (w < 4) {
      gload16(Kg + (size_t)(kt + rb + r8)     * (NKVH * HD) + (j8 ^ r8) * 8, &Ks[buf][rb][0]);
      gload16(Kg + (size_t)(kt + rb + 8 + r8) * (NKVH * HD) + (j8 ^ r8) * 8, &Ks[buf][rb + 8][0]);
    } else {
      gload16(Vg + (size_t)(rb + r8)     * S_LEN + kt + (j8 ^ r8) * 8, &Vs[buf][rb][0]);
      gload16(Vg + (size_t)(rb + 8 + r8) * S_LEN + kt + (j8 ^ r8) * 8, &Vs[buf][rb + 8][0]);
    }
  };
  auto ldK = [&](int buf, int row, int cidx) -> bf16x8_t {
    return *(const bf16x8_t*)&Ks[buf][row][(cidx ^ (row & 7)) * 8];
  };
  auto ldV = [&](int buf, int row, int cidx) -> bf16x8_t {
    return *(const bf16x8_t*)&Vs[buf][row][(cidx ^ (row & 7)) * 8];
  };

  stage(0, 0);
  __syncthreads();
  int cur = 0;
  const int NT = 2 * qt + 2;
  for (int t = 0; t < NT; ++t) {
    const int kt = t * 64;
    if (t + 1 < NT) stage(cur ^ 1, kt + 64);   // prefetch overlaps this tile's compute

    if (kt <= base_s + 15) {   // not fully masked for this wave
      // QK^T swapped: rows = keys, col = q = fr
      f32x4 sc[4];
#pragma unroll
      for (int c = 0; c < 4; ++c) {
        const int krow = c * 16 + fr;
        bf16x8_t k0 = ldK(cur, krow, fg);
        bf16x8_t k1 = ldK(cur, krow, 4 + fg);
        sc[c] = __builtin_amdgcn_mfma_f32_16x16x32_bf16(k0, qf[0], fz, 0, 0, 0);
        sc[c] = __builtin_amdgcn_mfma_f32_16x16x32_bf16(k1, qf[1], sc[c], 0, 0, 0);
      }

      // raw-domain max over own 16 keys (mask only in diagonal tiles)
      float p[4][4];
      float tm = -3.0e38f;
      if (kt + 63 > base_s) {
#pragma unroll
        for (int c = 0; c < 4; ++c)
#pragma unroll
          for (int r = 0; r < 4; ++r) {
            float v = sc[c][r];
            if (kt + c * 16 + fg * 4 + r > base_s + fr) v = -3.0e38f;
            p[c][r] = v; tm = fmaxf(tm, v);
          }
      } else {
#pragma unroll
        for (int c = 0; c < 4; ++c)
#pragma unroll
          for (int r = 0; r < 4; ++r) { p[c][r] = sc[c][r]; tm = fmaxf(tm, sc[c][r]); }
      }
      tm = fmaxf(tm, __shfl_xor(tm, 16));
      tm = fmaxf(tm, __shfl_xor(tm, 32));   // tm now uniform across fg for each q=fr

      // defer-max: rescale only when the max actually grew past threshold
      if (!__all(tm <= m_ + THRRAW)) {
        const float mnew = fmaxf(m_, tm);
        const float sf = exp2f((m_ - mnew) * CEXP);
        m_ = mnew;
        l_ *= sf;
        float sfv[4];
#pragma unroll
        for (int r = 0; r < 4; ++r) sfv[r] = __shfl(sf, fg * 4 + r);
#pragma unroll
        for (int fc = 0; fc < 4; ++fc)
#pragma unroll
          for (int r = 0; r < 4; ++r) acc[fc][r] *= sfv[r];
      }

      // p = exp2((raw - m) * SCALE*log2e); per-lane partial l
      float ts = 0.f;
#pragma unroll
      for (int c = 0; c < 4; ++c)
#pragma unroll
        for (int r = 0; r < 4; ++r) {
          p[c][r] = exp2f((p[c][r] - m_) * CEXP);
          ts += p[c][r];
        }
      l_ += ts;

      // P -> per-wave LDS [q][key], 8B packed stores
#pragma unroll
      for (int c = 0; c < 4; ++c) {
        __hip_bfloat16 b0 = __float2bfloat16(p[c][0]);
        __hip_bfloat16 b1 = __float2bfloat16(p[c][1]);
        __hip_bfloat16 b2 = __float2bfloat16(p[c][2]);
        __hip_bfloat16 b3 = __float2bfloat16(p[c][3]);
        ushort4 pk;
        pk.x = *(unsigned short*)&b0; pk.y = *(unsigned short*)&b1;
        pk.z = *(unsigned short*)&b2; pk.w = *(unsigned short*)&b3;
        *(ushort4*)&Ps[w][fr][c * 16 + fg * 4] = pk;
      }

      // PV: A = P (row q = fr), B = V (col d = fr)
#pragma unroll
      for (int kk = 0; kk < 2; ++kk) {
        bf16x8_t pa = *(const bf16x8_t*)&Ps[w][fr][kk * 32 + fg * 8];
#pragma unroll
        for (int fc = 0; fc < 4; ++fc) {
          bf16x8_t vf = ldV(cur, fc * 16 + fr, kk * 4 + fg);
          acc[fc] = __builtin_amdgcn_mfma_f32_16x16x32_bf16(pa, vf, acc[fc], 0, 0, 0);
        }
      }
    }

    __syncthreads();   // prefetch landed (compiler drains counts); all waves done with buf[cur]
    cur ^= 1;
  }

  // epilogue: finish l reduce (across fg), then normalize
  l_ += __shfl_xor(l_, 16);
  l_ += __shfl_xor(l_, 32);
  float lv[4];
#pragma unroll
  for (int r = 0; r < 4; ++r) lv[r] = __builtin_amdgcn_rcpf(__shfl(l_, fg * 4 + r));
#pragma unroll
  for (int fc = 0; fc < 4; ++fc)
#pragma unroll
    for (int r = 0; r < 4; ++r) {
      const size_t row = (size_t)(b * S_LEN + base_s + fg * 4 + r);
      O[row * DMODEL + h * HD + fc * 16 + fr] = __float2bfloat16(acc[fc][r] * lv[r]);
    }
}

// ---------------------------------------------------------------- launch
extern "C" void kernel_launch(void* const* d_in, const int* in_sizes, int n_in,
                              void* d_out, int out_size, void* d_ws, size_t ws_size,
                              hipStream_t stream)
{
  const float* x    = (const float*)d_in[0];
  const float* cosb = (const float*)d_in[1];
  const float* sinb = (const float*)d_in[2];
  const float* Wq   = (const float*)d_in[3];
  const float* Wk   = (const float*)d_in[4];
  const float* Wv   = (const float*)d_in[5];
  const float* Wo   = (const float*)d_in[6];
  float* out = (float*)d_out;

  char* p = (char*)d_ws;
  __hip_bfloat16* x_bf    = (__hip_bfloat16*)p; p += (size_t)NB * S_LEN * DMODEL * 2;
  __hip_bfloat16* Wq_bf   = (__hip_bfloat16*)p; p += (size_t)NH * HD * DMODEL * 2;
  __hip_bfloat16* Wk_bf   = (__hip_bfloat16*)p; p += (size_t)NKVH * HD * DMODEL * 2;
  __hip_bfloat16* Wv_bf   = (__hip_bfloat16*)p; p += (size_t)NKVH * HD * DMODEL * 2;
  __hip_bfloat16* Wo_bf   = (__hip_bfloat16*)p; p += (size_t)DMODEL * NH * HD * 2;
  __hip_bfloat16* Q_bf    = (__hip_bfloat16*)p; p += (size_t)NB * S_LEN * NH * HD * 2;
  __hip_bfloat16* K_bf    = (__hip_bfloat16*)p; p += (size_t)NB * S_LEN * NKVH * HD * 2;
  __hip_bfloat16* Vt_bf   = (__hip_bfloat16*)p; p += (size_t)NB * NKVH * HD * S_LEN * 2;
  __hip_bfloat16* attn_bf = (__hip_bfloat16*)p; p += (size_t)NB * S_LEN * NH * HD * 2;

  CvtArgs ca;
  ca.s[0] = { x,  x_bf,  (int)((size_t)NB * S_LEN * DMODEL / 4) };
  ca.s[1] = { Wq, Wq_bf, (int)((size_t)NH * HD * DMODEL / 4) };
  ca.s[2] = { Wk, Wk_bf, (int)((size_t)NKVH * HD * DMODEL / 4) };
  ca.s[3] = { Wv, Wv_bf, (int)((size_t)NKVH * HD * DMODEL / 4) };
  ca.s[4] = { Wo, Wo_bf, (int)((size_t)DMODEL * NH * HD / 4) };
  int total4 = ca.s[0].n4 + ca.s[1].n4 + ca.s[2].n4 + ca.s[3].n4 + ca.s[4].n4;
  cvt_all<<<(total4 + 255) / 256, 256, 0, stream>>>(ca);

  gemm_qkv<<<dim3(3072 / 128, (NB * S_LEN) / 128), dim3(256), 0, stream>>>(
      x_bf, Wq_bf, Wk_bf, Wv_bf, Q_bf, K_bf, Vt_bf, cosb, sinb);

  attn_kernel<<<dim3(S_LEN / 128, NB * NH), dim3(512), 0, stream>>>(Q_bf, K_bf, Vt_bf, attn_bf);

  gemm_o<<<dim3(DMODEL / 128, (NB * S_LEN) / 128), dim3(256), 0, stream>>>(attn_bf, Wo_bf, out);
}